// Round 13
// baseline (62.864 us; speedup 1.0000x reference)
//
#include <hip/hip_runtime.h>
#include <hip/hip_bf16.h>

// Dynamic conv2d: B=16, C_in=64, H=W=128, C_out=64, K=5, ks=3, pad=1.
// R13: 2 output rows per barrier step. B-fragments read ONCE per input row
// (48 ds_read_b128/wave/step) feeding dual accumulators; A-taps streamed
// from L2 per MFMA (no A-in-registers -> no spill pressure). Reg-staged
// pvA/pvB (loads at step start, LDS write after MFMA = full cover), 6-slot
// bf16 ring, raw s_barrier + lgkmcnt(0) (stores/loads in flight).

typedef __attribute__((ext_vector_type(8))) __bf16 bf16x8;
typedef __attribute__((ext_vector_type(16))) float f32x16;
typedef __attribute__((ext_vector_type(4))) unsigned int u32x4;

#define NB 16
#define CI 64
#define CO 64
#define HH 128
#define WW 128
#define KBANK 5
#define ASTR 36864            // shorts of aggw per b: 2m * 36ks * 2g * 32co5 * 8j

__device__ __forceinline__ unsigned short f2bfu(float f) {
    __hip_bfloat16 h = __float2bfloat16(f);
    unsigned short s;
    __builtin_memcpy(&s, &h, 2);
    return s;
}

// ---------------- kernel 1: aggregate weights + bias ----------------
// aggw per b: [m(2)][ks(36)][g(2)][co5(32)][j(8)]; k = ks*16+g*8+j,
// tap = k>>6, ci = k&63, co = m*32+co5. Wave A-load = contiguous 1KB.
__global__ void prep_kernel(const float* __restrict__ weights,
                            const float* __restrict__ Wbank,
                            const float* __restrict__ bbank,
                            short* __restrict__ aggw,
                            float* __restrict__ aggb) {
    int idx = blockIdx.x * 256 + threadIdx.x;          // < 16*36864
    int b   = idx / ASTR;
    int rem = idx - b * ASTR;
    int j   = rem & 7;
    int co5 = (rem >> 3) & 31;
    int g   = (rem >> 8) & 1;
    int mk  = rem >> 9;
    int m   = mk / 36;
    int ks  = mk - m * 36;
    int co  = m * 32 + co5;
    int k   = ks * 16 + g * 8 + j;
    int tap = k >> 6;
    int ci  = k & 63;
    float s = 0.f;
#pragma unroll
    for (int kk = 0; kk < KBANK; ++kk)
        s += weights[b * KBANK + kk] * Wbank[((kk * CO + co) * CI + ci) * 9 + tap];
    aggw[idx] = (short)f2bfu(s);
    if (k == 0) {
        float sb = 0.f;
#pragma unroll
        for (int kk = 0; kk < KBANK; ++kk)
            sb += weights[b * KBANK + kk] * bbank[kk * CO + co];
        aggb[b * CO + co] = sb;
    }
}

// ---------------- kernel 2: streaming conv ----------------
__device__ __forceinline__ void load16(const float* __restrict__ xb, int r,
                                       int sw, int scg, float (&pv)[16]) {
#pragma unroll
    for (int i = 0; i < 16; ++i)
        pv[i] = xb[((size_t)(scg * 16 + i) * HH + r) * WW + sw];
}

__device__ __forceinline__ void zero16(float (&pv)[16]) {
#pragma unroll
    for (int i = 0; i < 16; ++i) pv[i] = 0.f;
}

// ring slot: [ch 8][pix 130][8 shorts]; pix = input w + 1.
__device__ __forceinline__ void write16(short* __restrict__ slot, int sw, int scg,
                                        const float (&pv)[16]) {
#pragma unroll
    for (int h = 0; h < 2; ++h) {
        unsigned u0 = (unsigned)f2bfu(pv[h * 8 + 0]) | ((unsigned)f2bfu(pv[h * 8 + 1]) << 16);
        unsigned u1 = (unsigned)f2bfu(pv[h * 8 + 2]) | ((unsigned)f2bfu(pv[h * 8 + 3]) << 16);
        unsigned u2 = (unsigned)f2bfu(pv[h * 8 + 4]) | ((unsigned)f2bfu(pv[h * 8 + 5]) << 16);
        unsigned u3 = (unsigned)f2bfu(pv[h * 8 + 6]) | ((unsigned)f2bfu(pv[h * 8 + 7]) << 16);
        *(u32x4*)&slot[((scg * 2 + h) * 130 + sw + 1) * 8] = u32x4{u0, u1, u2, u3};
    }
}

#define WAITL0   asm volatile("s_waitcnt lgkmcnt(0)" ::: "memory")
#define SBAR     do { __builtin_amdgcn_s_barrier(); __builtin_amdgcn_sched_barrier(0); } while (0)

__global__ __launch_bounds__(512, 2) void conv_kernel(const float* __restrict__ x,
                                                      const short* __restrict__ aggw,
                                                      const float* __restrict__ aggb,
                                                      float* __restrict__ out) {
    __shared__ short bring[6][8][130][8];              // 99,840 B

    const int t   = threadIdx.x;
    const int lin = blockIdx.x;                        // 256 blocks
    const int b   = (lin & 7) * 2 + ((lin >> 3) & 1);  // same-b blocks share an XCD
    const int r0  = (lin >> 4) * 8;                    // 8-row strip

    const int l  = t & 63;
    const int wv = t >> 6;         // 0..7
    const int m  = wv >> 2;        // co half
    const int nq = wv & 3;         // pix quarter
    const int lm = l & 31;
    const int g  = l >> 5;

    const int sw  = t & 127;       // staging: w
    const int scg = t >> 7;        // staging: 16-ci group

    const float* xb = x + (size_t)b * CI * HH * WW;
    const short* Ab = aggw + (size_t)b * ASTR + (size_t)m * 36 * 512 + l * 8;

    float bias[16];
#pragma unroll
    for (int rg = 0; rg < 16; ++rg)
        bias[rg] = aggb[b * CO + m * 32 + (rg & 3) + 8 * (rg >> 2) + 4 * g];

    // zero pix-halo (pix 0 and 129) of all 6 slots
    if (t < 96) {
        int slot = t >> 4, ch = (t >> 1) & 7, px = (t & 1) * 129;
        *(u32x4*)&bring[slot][ch][px][0] = u32x4{0u, 0u, 0u, 0u};
    }

    float pvA[16], pvB[16];
    // ---- prologue: rows r0-1..r0+2 -> slots 0..3 ----
    if (r0 > 0) load16(xb, r0 - 1, sw, scg, pvA); else zero16(pvA);
    load16(xb, r0, sw, scg, pvB);
    write16(&bring[0][0][0][0], sw, scg, pvA);
    write16(&bring[1][0][0][0], sw, scg, pvB);
    load16(xb, r0 + 1, sw, scg, pvA);
    load16(xb, r0 + 2, sw, scg, pvB);
    write16(&bring[2][0][0][0], sw, scg, pvA);
    write16(&bring[3][0][0][0], sw, scg, pvB);
    WAITL0; SBAR;

    // ---- 4 double-row steps ----
#pragma unroll
    for (int s = 0; s < 4; ++s) {
        const int rA = r0 + 2 * s;                     // output rows rA, rA+1

        // issue staging loads for rows rA+3, rA+4 (consumed by write16 below)
        if (s < 3) {
            load16(xb, rA + 3, sw, scg, pvA);          // rA+3 <= 127 always (s<3)
            if (rA + 4 <= 127) load16(xb, rA + 4, sw, scg, pvB);
            else               zero16(pvB);
        }

        f32x16 accA = (f32x16)0.0f;
        f32x16 accB = (f32x16)0.0f;

        // input rows rA-1+rho, rho=0..3; each B-fragment read ONCE.
        // accA taps: dy=rho (rho<3); accB taps: dy=rho-1 (rho>0).
#pragma unroll
        for (int rho = 0; rho < 4; ++rho) {
            const short* sb = &bring[(2 * s + rho) % 6][0][0][0];
#pragma unroll
            for (int dx = 0; dx < 3; ++dx) {
#pragma unroll
                for (int q = 0; q < 4; ++q) {
                    const int pix = nq * 32 + lm + dx;
                    bf16x8 bv = *(const bf16x8*)&sb[((q * 2 + g) * 130 + pix) * 8];
                    if (rho < 3) {
                        bf16x8 a = *(const bf16x8*)(Ab + (((rho)*3 + dx) * 4 + q) * 512);
                        accA = __builtin_amdgcn_mfma_f32_32x32x16_bf16(a, bv, accA, 0, 0, 0);
                    }
                    if (rho > 0) {
                        bf16x8 a = *(const bf16x8*)(Ab + (((rho - 1) * 3 + dx) * 4 + q) * 512);
                        accB = __builtin_amdgcn_mfma_f32_32x32x16_bf16(a, bv, accB, 0, 0, 0);
                    }
                }
            }
        }

        // output stores (fire-and-forget; stay in flight across the barrier)
        const int wc = nq * 32 + lm;
#pragma unroll
        for (int rg = 0; rg < 16; ++rg) {
            int co = m * 32 + (rg & 3) + 8 * (rg >> 2) + 4 * g;
            out[(((size_t)b * CO + co) * HH + rA) * WW + wc] = accA[rg] + bias[rg];
        }
#pragma unroll
        for (int rg = 0; rg < 16; ++rg) {
            int co = m * 32 + (rg & 3) + 8 * (rg >> 2) + 4 * g;
            out[(((size_t)b * CO + co) * HH + (rA + 1)) * WW + wc] = accB[rg] + bias[rg];
        }

        // stage rows rA+3, rA+4 into slots (2s+4)%6, (2s+5)%6
        if (s < 3) {
            write16(&bring[(2 * s + 4) % 6][0][0][0], sw, scg, pvA);
            write16(&bring[(2 * s + 5) % 6][0][0][0], sw, scg, pvB);
        }

        WAITL0; SBAR;
    }
}

extern "C" void kernel_launch(void* const* d_in, const int* in_sizes, int n_in,
                              void* d_out, int out_size, void* d_ws, size_t ws_size,
                              hipStream_t stream) {
    const float* x       = (const float*)d_in[0];
    const float* weights = (const float*)d_in[1];
    const float* Wbank   = (const float*)d_in[2];
    const float* bbank   = (const float*)d_in[3];
    float* out = (float*)d_out;

    short* aggw = (short*)d_ws;                          // 1,179,648 B
    float* aggb = (float*)((char*)d_ws + 1179648);       //     4,096 B

    prep_kernel<<<dim3((NB * ASTR) / 256), dim3(256), 0, stream>>>(weights, Wbank, bbank, aggw, aggb);
    conv_kernel<<<dim3(256), dim3(512), 0, stream>>>(x, aggw, aggb, out);
}